// Round 10
// baseline (2521.886 us; speedup 1.0000x reference)
//
#include <hip/hip_runtime.h>

typedef __attribute__((ext_vector_type(8))) short short8;
typedef __attribute__((ext_vector_type(4))) float floatx4;
typedef __attribute__((ext_vector_type(2))) unsigned long long ull2;

// ---------- helpers ----------
__device__ __forceinline__ unsigned short f2bf(float f) {
  unsigned int u = __float_as_uint(f);
  unsigned int lsb = (u >> 16) & 1u;
  u += 0x7fffu + lsb;  // round-to-nearest-even
  return (unsigned short)(u >> 16);
}
__device__ __forceinline__ float bf2f(unsigned short u) {
  unsigned int x = ((unsigned int)u) << 16;
  return __uint_as_float(x);
}
__device__ __forceinline__ float sigm(float x) { return 1.f / (1.f + __expf(-x)); }
__device__ __forceinline__ float tanh_fast(float x) { return 2.f / (1.f + __expf(-2.f * x)) - 1.f; }
__device__ __forceinline__ floatx4 mfma16(short8 a, short8 b, floatx4 c) {
  return __builtin_amdgcn_mfma_f32_16x16x32_bf16(a, b, c, 0, 0, 0);
}

// ---------- fused prep: Wc/bc + 5 bf16 converts + b1, one launch ----------
// (unchanged -- the gate-fusion remap is a per-lane address change in persist)
__global__ __launch_bounds__(256) void prep_kernel(
    const float* __restrict__ Wih0, const float* __restrict__ inW,
    const float* __restrict__ inb, const float* __restrict__ bih0,
    const float* __restrict__ bhh0, const float* __restrict__ Whh0,
    const float* __restrict__ Whh1, const float* __restrict__ Wih1,
    const float* __restrict__ tahW, const float* __restrict__ taW,
    const float* __restrict__ bih1, const float* __restrict__ bhh1,
    unsigned short* __restrict__ Wc, float* __restrict__ bc,
    unsigned short* __restrict__ Whh0b, unsigned short* __restrict__ Whh1b,
    unsigned short* __restrict__ Wih1b, unsigned short* __restrict__ tahWb,
    unsigned short* __restrict__ taWb, float* __restrict__ b1) {
  const int b = blockIdx.x, tid = threadIdx.x;
  if (b < 512) {  // Wc = Wih0 @ in_W; bc = Wih0@in_b + bih0 + bhh0
    const int n = b * 2 + (tid >> 7), k = tid & 127;
    float a = 0.f;
    for (int j = 0; j < 256; ++j) a += Wih0[n * 256 + j] * inW[j * 128 + k];
    Wc[n * 128 + k] = f2bf(a);
    if (k == 0) {
      float bs = bih0[n] + bhh0[n];
      for (int j = 0; j < 256; ++j) bs += Wih0[n * 256 + j] * inb[j];
      bc[n] = bs;
    }
  } else if (b < 896) {
    const int bb = b - 512;
    const float* src = (bb < 128) ? Whh0 : (bb < 256) ? Whh1 : Wih1;
    unsigned short* dst = (bb < 128) ? Whh0b : (bb < 256) ? Whh1b : Wih1b;
    const int off = (bb & 127) * 2048 + tid * 8;
    short8 v;
#pragma unroll
    for (int u = 0; u < 8; ++u) v[u] = (short)f2bf(src[off + u]);
    *(short8*)&dst[off] = v;
  } else if (b < 912) {
    const int off = (b - 896) * 2048 + tid * 8;
    short8 v;
#pragma unroll
    for (int u = 0; u < 8; ++u) v[u] = (short)f2bf(tahW[off + u]);
    *(short8*)&tahWb[off] = v;
  } else if (b < 920) {
    const int off = (b - 912) * 2048 + tid * 8;
    short8 v;
#pragma unroll
    for (int u = 0; u < 8; ++u) v[u] = (short)f2bf(taW[off + u]);
    *(short8*)&taWb[off] = v;
  } else {
#pragma unroll
    for (int u = 0; u < 4; ++u) {
      const int i = tid * 4 + u;
      b1[i] = bih1[i] + bhh1[i];
    }
  }
}

// ---------- BatchNorm + spatial attention, MFMA version (unchanged) ----------
__global__ __launch_bounds__(256) void bnsa_kernel(
    const float* __restrict__ x, const float* __restrict__ gamma,
    const float* __restrict__ beta, const float* __restrict__ mean,
    const float* __restrict__ var, const float* __restrict__ saW,
    const float* __restrict__ sab, unsigned short* __restrict__ xs) {
  __shared__ unsigned short saWs[128 * 132];  // [n][k] bf16 (reused as xs staging)
  __shared__ unsigned short xbb[128 * 136];   // [m][k] bf16
  const int tid = threadIdx.x;
  const int wv = tid >> 6, lane = tid & 63;
  const int lm = lane & 15, q = lane >> 4;
  const long r0 = (long)blockIdx.x * 128;

  for (int i = tid; i < 16384; i += 256) saWs[(i >> 7) * 132 + (i & 127)] = f2bf(saW[i]);
  {
    const int k0 = tid & 127;
    const float mn = mean[k0];
    const float is = rsqrtf(var[k0] + 1e-5f) * gamma[k0];
    const float bt = beta[k0];
    for (int i = tid; i < 16384; i += 256) {  // stride 256 keeps k fixed per thread
      const int m = i >> 7;
      xbb[m * 136 + k0] = f2bf((x[(r0 + m) * 128 + k0] - mn) * is + bt);
    }
  }
  __syncthreads();

  short8 af[2][4];
#pragma unroll
  for (int mt = 0; mt < 2; ++mt)
#pragma unroll
    for (int kt = 0; kt < 4; ++kt)
      af[mt][kt] = *(const short8*)&xbb[(wv * 32 + mt * 16 + lm) * 136 + kt * 32 + q * 8];

  floatx4 acc[2][8];
#pragma unroll
  for (int nt = 0; nt < 8; ++nt) {
    const float sb = sab[nt * 16 + lm];
    short8 bf[4];
#pragma unroll
    for (int kt = 0; kt < 4; ++kt)
      bf[kt] = *(const short8*)&saWs[(nt * 16 + lm) * 132 + kt * 32 + q * 8];
#pragma unroll
    for (int mt = 0; mt < 2; ++mt) {
      floatx4 a = (floatx4){sb, sb, sb, sb};
#pragma unroll
      for (int kt = 0; kt < 4; ++kt) a = mfma16(af[mt][kt], bf[kt], a);
      acc[mt][nt] = a;
    }
  }
  // e = exp(sigmoid(S)); row sums across the 16 lm lanes (full 128 cols per row)
  float tot[2][4];
#pragma unroll
  for (int mt = 0; mt < 2; ++mt)
#pragma unroll
    for (int r = 0; r < 4; ++r) {
      float p = 0.f;
#pragma unroll
      for (int nt = 0; nt < 8; ++nt) {
        const float e = __expf(sigm(acc[mt][nt][r]));
        acc[mt][nt][r] = e;
        p += e;
      }
      p += __shfl_xor(p, 1);
      p += __shfl_xor(p, 2);
      p += __shfl_xor(p, 4);
      p += __shfl_xor(p, 8);
      tot[mt][r] = p;
    }
  __syncthreads();  // all saWs B-frag reads done -> reuse as staging
  unsigned short* stg = saWs;  // [128][128]
#pragma unroll
  for (int nt = 0; nt < 8; ++nt) {
    const int col = nt * 16 + lm;
    const float mn = mean[col];
    const float is = rsqrtf(var[col] + 1e-5f) * gamma[col];
    const float bt = beta[col];
#pragma unroll
    for (int mt = 0; mt < 2; ++mt)
#pragma unroll
      for (int r = 0; r < 4; ++r) {
        const int row = wv * 32 + mt * 16 + q * 4 + r;  // C/D: row=quad*4+reg, col=lane&15
        const float xb = (x[(r0 + row) * 128 + col] - mn) * is + bt;
        stg[row * 128 + col] = f2bf(xb * (acc[mt][nt][r] / tot[mt][r]));
      }
  }
  __syncthreads();
  for (int i = tid * 8; i < 16384; i += 2048)
    *(short8*)&xs[r0 * 128 + i] = *(const short8*)&stg[i];
}

// ---------- N-split persistent kernel: in-wave gate fusion ----------
// Round-17 delta: delete B1 + gatebuf. B-operand lanes remapped so each wave
// owns 4 gate types x 4 cols (ng = (lm>>2)*256 + slice*32 + wv*4 + (lm&3))
// instead of 1 gate type x 16 cols. The 4 gate values for a column now live
// in 4 lanes of the SAME wave at lm-stride 4 -> cell = 4 __shfl per acc row
// (in-register), no LDS staging, no barrier. Effects: (1) publish issues
// ~500cy earlier (no B1 wait) so remote visibility overlaps ta/B2/sa;
// (2) 2 barriers/step instead of 3; (3) gatebuf (40KB LDS, stride-20 bank
// traffic) deleted; (4) all 8 waves share cells and the poll (4 loads/thread
// vs 8 on half the waves). Exchange layout/protocol byte-identical to the
// proven baseline (entry = gcol*4+q, per-8B tags, relaxed agent stores,
// self-validating tag poll).
__global__ __launch_bounds__(512, 2) void persist_kernel(
    const unsigned short* __restrict__ xs,  // [B,T,128] bf16
    const unsigned short* __restrict__ Wc, const float* __restrict__ bc,
    const unsigned short* __restrict__ Whh0,
    const unsigned short* __restrict__ Wih1, const float* __restrict__ b1,
    const unsigned short* __restrict__ Whh1,
    const unsigned short* __restrict__ tahWg, const float* __restrict__ tahb,
    const unsigned short* __restrict__ taWg, const float* __restrict__ tab,
    const float* __restrict__ outW,
    ull2* __restrict__ ex,  // [2 parity][16 group][2 layer][1024 entries] x 16B = 1 MB
    float* __restrict__ out) {
  __shared__ unsigned short tahWs[128 * 264];  // [f][k], k<256   67584 B
  __shared__ unsigned short taWs[128 * 136];   // [f][j], j<128   34816 B
  __shared__ unsigned short h0buf[16 * 264];   //                  8448 B
  __shared__ unsigned short h1buf[16 * 264];   //                  8448 B
  __shared__ unsigned short totB[16 * 136];    //                  4352 B
  // total 123648 B (gatebuf deleted; 'red' reduction reuses tahWs)

  const int tid = threadIdx.x;
  const int wv = tid >> 6, lane = tid & 63;
  const int lm = lane & 15, q = lane >> 4;
  const int slice = blockIdx.x >> 4, group = blockIdx.x & 15;
  const int b0 = group * 16;
  const int lcol = lm & 3;  // local col 0..3 within the wave's 4-col tile
  // fused mapping: lane lm = gate (lm>>2) x col (lm&3); wave covers cols
  // slice*32 + wv*4 .. +3 for ALL 4 gates of both layers.
  const int ng = (lm >> 2) * 256 + slice * 32 + wv * 4 + lcol;
  const int fcol = wv * 16 + lm;  // attention col (8 waves x 16 = 128)

  for (int i = tid; i < 128 * 256; i += 512) tahWs[(i >> 8) * 264 + (i & 255)] = tahWg[i];
  for (int i = tid; i < 128 * 128; i += 512) taWs[(i >> 7) * 136 + (i & 127)] = taWg[i];
  for (int i = tid; i < 16 * 264; i += 512) { h0buf[i] = 0; h1buf[i] = 0; }

  // register-resident weight B-frags (loaded once; same 112 VGPR footprint,
  // rows selected by the fused ng mapping -- no memory re-layout needed)
  short8 Wcf[4], W0f[8], W1if[8], W1hf[8];
#pragma unroll
  for (int kt = 0; kt < 4; ++kt) Wcf[kt] = *(const short8*)&Wc[(size_t)ng * 128 + kt * 32 + q * 8];
#pragma unroll
  for (int kt = 0; kt < 8; ++kt) {
    W0f[kt] = *(const short8*)&Whh0[(size_t)ng * 256 + kt * 32 + q * 8];
    W1if[kt] = *(const short8*)&Wih1[(size_t)ng * 256 + kt * 32 + q * 8];
    W1hf[kt] = *(const short8*)&Whh1[(size_t)ng * 256 + kt * 32 + q * 8];
  }
  const float bcv = bc[ng], b1v = b1[ng];
  const float tahbv = tahb[fcol], tabv = tab[fcol], outWv = outW[fcol];

  floatx4 cst0 = (floatx4){0.f, 0.f, 0.f, 0.f};  // cell state, col lcol (4x lane-redundant)
  floatx4 cst1 = (floatx4){0.f, 0.f, 0.f, 0.f};
  float num[4] = {0.f, 0.f, 0.f, 0.f}, den[4] = {0.f, 0.f, 0.f, 0.f};

  const unsigned short* xrow = xs + (size_t)(b0 + lm) * 65536 + q * 8;
  short8 axf[4], axn[4];
#pragma unroll
  for (int kt = 0; kt < 4; ++kt) axf[kt] = *(const short8*)(xrow + kt * 32);

  // writer entry (lanes lm<4 publish): entry = gcol*4 + q, same global layout
  const int ew = (slice * 32 + wv * 4 + lcol) * 4 + q;
  ull2* const exg = ex + (size_t)group * 2048;  // [2 layer][1024] per parity via +p*32768

  // reader: all 8 waves; thread nt in 0..511 handles entries {nt, nt+512}/layer
  const int nt = wv * 64 + lane;
  unsigned voBase[4];
#pragma unroll
  for (int L = 0; L < 2; ++L)
#pragma unroll
    for (int j = 0; j < 2; ++j) voBase[L * 2 + j] = (unsigned)((L * 1024 + j * 512 + nt) << 4);
  const int cb = nt >> 2, qq = nt & 3;  // entry nt -> col cb; nt+512 -> col cb+128

  __syncthreads();

  for (int t = 0; t <= 512; ++t) {
    const int p = t & 1;
    const unsigned fvu = (unsigned)(t + 1);

    // ---- gates0(t) = xs_t @ Wc^T + h0_{t-1} @ Whh0^T + bc ----
    floatx4 acc0;
    {
      floatx4 aW = (floatx4){0.f, 0.f, 0.f, 0.f};
      floatx4 aH = (floatx4){bcv, bcv, bcv, bcv};
#pragma unroll
      for (int kt = 0; kt < 4; ++kt) aW = mfma16(axf[kt], Wcf[kt], aW);
#pragma unroll
      for (int kt = 0; kt < 8; ++kt) {
        const short8 a = *(const short8*)&h0buf[lm * 264 + kt * 32 + q * 8];
        aH = mfma16(a, W0f[kt], aH);
      }
      acc0 = aW + aH;
    }
    {  // prefetch next xs frags (clamped)
      const size_t tn = (t < 511) ? t + 1 : 511;
#pragma unroll
      for (int kt = 0; kt < 4; ++kt) axn[kt] = *(const short8*)(xrow + tn * 128 + kt * 32);
    }
    // ---- gates1(t-1) = h0_{t-1} @ Wih1^T + h1_{t-2} @ Whh1^T + b1 ----
    floatx4 acc1;
    {
      floatx4 aI = (floatx4){b1v, b1v, b1v, b1v};
      floatx4 aH = (floatx4){0.f, 0.f, 0.f, 0.f};
#pragma unroll
      for (int kt = 0; kt < 8; ++kt) {
        const short8 a = *(const short8*)&h0buf[lm * 264 + kt * 32 + q * 8];
        aI = mfma16(a, W1if[kt], aI);
      }
#pragma unroll
      for (int kt = 0; kt < 8; ++kt) {
        const short8 a = *(const short8*)&h1buf[lm * 264 + kt * 32 + q * 8];
        aH = mfma16(a, W1hf[kt], aH);
      }
      acc1 = aI + aH;
    }

    // ---- in-wave cells via shuffle (NO barrier, NO LDS staging) ----
    // lane (q,lm) gathers the 4 gate values for col lcol, rows q*4+r from
    // lanes q*16 + gate*4 + lcol. All lanes compute (4x redundant); cst is
    // consistent across the redundancy group.
    const int shbase = (lane & 48) | lcol;
    unsigned short hb0[4], hb1[4];
#pragma unroll
    for (int r = 0; r < 4; ++r) {
      const float iv = __shfl(acc0[r], shbase + 0);
      const float fv = __shfl(acc0[r], shbase + 4);
      const float gv = __shfl(acc0[r], shbase + 8);
      const float ov = __shfl(acc0[r], shbase + 12);
      const float cn = sigm(fv) * cst0[r] + sigm(iv) * tanh_fast(gv);
      cst0[r] = cn;
      hb0[r] = f2bf(sigm(ov) * tanh_fast(cn));
    }
    if (t > 0) {
#pragma unroll
      for (int r = 0; r < 4; ++r) {
        const float iv = __shfl(acc1[r], shbase + 0);
        const float fv = __shfl(acc1[r], shbase + 4);
        const float gv = __shfl(acc1[r], shbase + 8);
        const float ov = __shfl(acc1[r], shbase + 12);
        const float cn = sigm(fv) * cst1[r] + sigm(iv) * tanh_fast(gv);
        cst1[r] = cn;
        hb1[r] = f2bf(sigm(ov) * tanh_fast(cn));
      }
    } else {
#pragma unroll
      for (int r = 0; r < 4; ++r) hb1[r] = 0;
    }

    // ---- fire-and-forget publish (lanes lm<4: both layers, 2 entries) ----
    if (lm < 4) {
      const unsigned long long sq = (unsigned long long)fvu << 32;
      const unsigned long long qlo0 = (unsigned long long)hb0[0] | ((unsigned long long)hb0[1] << 16) | sq;
      const unsigned long long qhi0 = (unsigned long long)hb0[2] | ((unsigned long long)hb0[3] << 16) | sq;
      const unsigned long long qlo1 = (unsigned long long)hb1[0] | ((unsigned long long)hb1[1] << 16) | sq;
      const unsigned long long qhi1 = (unsigned long long)hb1[2] | ((unsigned long long)hb1[3] << 16) | sq;
      unsigned long long* wp0 = (unsigned long long*)(exg + (size_t)p * 32768 + ew);
      unsigned long long* wp1 = (unsigned long long*)(exg + (size_t)p * 32768 + 1024 + ew);
      __hip_atomic_store(&wp0[0], qlo0, __ATOMIC_RELAXED, __HIP_MEMORY_SCOPE_AGENT);
      __hip_atomic_store(&wp0[1], qhi0, __ATOMIC_RELAXED, __HIP_MEMORY_SCOPE_AGENT);
      __hip_atomic_store(&wp1[0], qlo1, __ATOMIC_RELAXED, __HIP_MEMORY_SCOPE_AGENT);
      __hip_atomic_store(&wp1[1], qhi1, __ATOMIC_RELAXED, __HIP_MEMORY_SCOPE_AGENT);
    }

    // ---- attention-total on h1_{t-2} (all 8 waves; data flies meanwhile) ----
    floatx4 ta;
    if (t >= 2) {
      ta = (floatx4){tahbv, tahbv, tahbv, tahbv};
#pragma unroll
      for (int kt = 0; kt < 8; ++kt) {
        const short8 a = *(const short8*)&h1buf[lm * 264 + kt * 32 + q * 8];
        ta = mfma16(a, *(const short8*)&tahWs[fcol * 264 + kt * 32 + q * 8], ta);
      }
#pragma unroll
      for (int r = 0; r < 4; ++r) totB[(q * 4 + r) * 136 + fcol] = f2bf(ta[r]);
    }
    __syncthreads();  // B2: totB ready; all h0/h1buf reads done (scatter may overwrite)
    if (t >= 2) {
      floatx4 sa = (floatx4){tabv, tabv, tabv, tabv};
#pragma unroll
      for (int kt = 0; kt < 4; ++kt) {
        const short8 a = *(const short8*)&totB[lm * 136 + kt * 32 + q * 8];
        sa = mfma16(a, *(const short8*)&taWs[fcol * 136 + kt * 32 + q * 8], sa);
      }
#pragma unroll
      for (int r = 0; r < 4; ++r) {
        const float e = __expf(fmaxf(sa[r], 0.f));  // relu(spre) in [0,~1]: safe
        num[r] += e * ta[r];
        den[r] += e;
      }
    }

    // ---- poll+scatter (ALL 8 waves, 4 loads each): detect == transfer ----
    {
      const unsigned pterm = (unsigned)p << 19;  // p*32768 entries *16B
      const unsigned v0o = voBase[0] + pterm, v1o = voBase[1] + pterm;
      const unsigned v2o = voBase[2] + pterm, v3o = voBase[3] + pterm;
      ull2 d0, d1, e0, e1;
      unsigned bad;
      do {
        asm volatile(
            "global_load_dwordx4 %0, %4, %8 sc0 sc1\n\t"
            "global_load_dwordx4 %1, %5, %8 sc0 sc1\n\t"
            "global_load_dwordx4 %2, %6, %8 sc0 sc1\n\t"
            "global_load_dwordx4 %3, %7, %8 sc0 sc1\n\t"
            "s_waitcnt vmcnt(0)"
            : "=&v"(d0), "=&v"(d1), "=&v"(e0), "=&v"(e1)
            : "v"(v0o), "v"(v1o), "v"(v2o), "v"(v3o),
              "s"(exg)
            : "memory");
        bad = ((unsigned)(d0.x >> 32) != fvu) | ((unsigned)(d0.y >> 32) != fvu) |
              ((unsigned)(d1.x >> 32) != fvu) | ((unsigned)(d1.y >> 32) != fvu) |
              ((unsigned)(e0.x >> 32) != fvu) | ((unsigned)(e0.y >> 32) != fvu) |
              ((unsigned)(e1.x >> 32) != fvu) | ((unsigned)(e1.y >> 32) != fvu);
      } while (bad);
      // scatter: entry nt -> col cb; entry nt+512 -> col cb+128; rows qq*4..+3
      {
        const int c0 = cb, c1 = 128 + cb;
        h0buf[(qq * 4 + 0) * 264 + c0] = (unsigned short)d0.x;
        h0buf[(qq * 4 + 1) * 264 + c0] = (unsigned short)(d0.x >> 16);
        h0buf[(qq * 4 + 2) * 264 + c0] = (unsigned short)d0.y;
        h0buf[(qq * 4 + 3) * 264 + c0] = (unsigned short)(d0.y >> 16);
        h0buf[(qq * 4 + 0) * 264 + c1] = (unsigned short)d1.x;
        h0buf[(qq * 4 + 1) * 264 + c1] = (unsigned short)(d1.x >> 16);
        h0buf[(qq * 4 + 2) * 264 + c1] = (unsigned short)d1.y;
        h0buf[(qq * 4 + 3) * 264 + c1] = (unsigned short)(d1.y >> 16);
        h1buf[(qq * 4 + 0) * 264 + c0] = (unsigned short)e0.x;
        h1buf[(qq * 4 + 1) * 264 + c0] = (unsigned short)(e0.x >> 16);
        h1buf[(qq * 4 + 2) * 264 + c0] = (unsigned short)e0.y;
        h1buf[(qq * 4 + 3) * 264 + c0] = (unsigned short)(e0.y >> 16);
        h1buf[(qq * 4 + 0) * 264 + c1] = (unsigned short)e1.x;
        h1buf[(qq * 4 + 1) * 264 + c1] = (unsigned short)(e1.x >> 16);
        h1buf[(qq * 4 + 2) * 264 + c1] = (unsigned short)e1.y;
        h1buf[(qq * 4 + 3) * 264 + c1] = (unsigned short)(e1.y >> 16);
      }
    }
    __syncthreads();  // B3: h0buf=h0_t, h1buf=h1_{t-1}

#pragma unroll
    for (int kt = 0; kt < 4; ++kt) axf[kt] = axn[kt];
  }

  // ---- tail: attention on h1_{511} (last receive) ----
  {
    floatx4 ta = (floatx4){tahbv, tahbv, tahbv, tahbv};
#pragma unroll
    for (int kt = 0; kt < 8; ++kt) {
      const short8 a = *(const short8*)&h1buf[lm * 264 + kt * 32 + q * 8];
      ta = mfma16(a, *(const short8*)&tahWs[fcol * 264 + kt * 32 + q * 8], ta);
    }
#pragma unroll
    for (int r = 0; r < 4; ++r) totB[(q * 4 + r) * 136 + fcol] = f2bf(ta[r]);
    __syncthreads();
    floatx4 sa = (floatx4){tabv, tabv, tabv, tabv};
#pragma unroll
    for (int kt = 0; kt < 4; ++kt) {
      const short8 a = *(const short8*)&totB[lm * 136 + kt * 32 + q * 8];
      sa = mfma16(a, *(const short8*)&taWs[fcol * 136 + kt * 32 + q * 8], sa);
    }
#pragma unroll
    for (int r = 0; r < 4; ++r) {
      const float e = __expf(fmaxf(sa[r], 0.f));
      num[r] += e * ta[r];
      den[r] += e;
    }
  }
  __syncthreads();

  // ---- out[b] = sum_f (num/den)*outW ----
  float* red = (float*)&tahWs[0];  // reuse (>= 16*136 floats; tahWs reads done)
#pragma unroll
  for (int r = 0; r < 4; ++r) red[(q * 4 + r) * 136 + fcol] = (num[r] / den[r]) * outWv;
  __syncthreads();
  if (slice == 0 && tid < 16) {
    float s = 0.f;
    for (int k = 0; k < 128; ++k) s += red[tid * 136 + k];
    out[b0 + tid] = s;
  }
}

// ---------- host ----------
extern "C" void kernel_launch(void* const* d_in, const int* in_sizes, int n_in,
                              void* d_out, int out_size, void* d_ws, size_t ws_size,
                              hipStream_t stream) {
  (void)in_sizes; (void)n_in; (void)out_size; (void)ws_size;
  const float* x    = (const float*)d_in[0];
  const float* bng  = (const float*)d_in[1];
  const float* bnb  = (const float*)d_in[2];
  const float* bnm  = (const float*)d_in[3];
  const float* bnv  = (const float*)d_in[4];
  const float* saW  = (const float*)d_in[5];
  const float* sab  = (const float*)d_in[6];
  const float* inW  = (const float*)d_in[7];
  const float* inb  = (const float*)d_in[8];
  const float* Wih0 = (const float*)d_in[9];
  const float* Whh0 = (const float*)d_in[10];
  const float* bih0 = (const float*)d_in[11];
  const float* bhh0 = (const float*)d_in[12];
  const float* Wih1 = (const float*)d_in[13];
  const float* Whh1 = (const float*)d_in[14];
  const float* bih1 = (const float*)d_in[15];
  const float* bhh1 = (const float*)d_in[16];
  const float* tahW = (const float*)d_in[17];
  const float* tahb = (const float*)d_in[18];
  const float* taW  = (const float*)d_in[19];
  const float* tab  = (const float*)d_in[20];
  const float* outW = (const float*)d_in[21];
  float* out = (float*)d_out;

  char* ws = (char*)d_ws;
  size_t off = 0;
  auto alloc = [&](size_t bytes) {
    char* p = ws + off;
    off += (bytes + 255) & ~(size_t)255;
    return p;
  };
  unsigned short* Wc    = (unsigned short*)alloc((size_t)1024 * 128 * 2);
  float* bc             = (float*)alloc(1024 * 4);
  float* b1             = (float*)alloc(1024 * 4);
  unsigned short* Whh0b = (unsigned short*)alloc((size_t)1024 * 256 * 2);
  unsigned short* Whh1b = (unsigned short*)alloc((size_t)1024 * 256 * 2);
  unsigned short* Wih1b = (unsigned short*)alloc((size_t)1024 * 256 * 2);
  unsigned short* tahWb = (unsigned short*)alloc((size_t)128 * 256 * 2);
  unsigned short* taWb  = (unsigned short*)alloc((size_t)128 * 128 * 2);
  unsigned short* xs    = (unsigned short*)alloc((size_t)131072 * 128 * 2);
  ull2* ex              = (ull2*)alloc((size_t)2 * 16 * 2 * 1024 * 16);  // 1 MB

  hipLaunchKernelGGL(prep_kernel, dim3(921), dim3(256), 0, stream, Wih0, inW, inb, bih0, bhh0,
                     Whh0, Whh1, Wih1, tahW, taW, bih1, bhh1, Wc, bc, Whh0b, Whh1b, Wih1b,
                     tahWb, taWb, b1);
  hipLaunchKernelGGL(bnsa_kernel, dim3(1024), dim3(256), 0, stream, x, bng, bnb, bnm, bnv, saW,
                     sab, xs);
  hipLaunchKernelGGL(persist_kernel, dim3(128), dim3(512), 0, stream, xs, Wc, bc, Whh0b, Wih1b,
                     b1, Whh1b, tahWb, tahb, taWb, tab, outW, ex, out);
}